// Round 1
// baseline (1131.997 us; speedup 1.0000x reference)
//
#include <hip/hip_runtime.h>
#include <cmath>

#define B_    8
#define NIN_  256
#define D_    128
#define K_    1024
#define N_    4096
#define P_    (B_ * N_)          // 32768 positions

// ---- workspace layout (bytes) ----
#define WS_ZSUM   0                         // K_*D_*4 = 524288
#define WS_NSUM   (WS_ZSUM + K_ * D_ * 4)   // 524288 (K_*4 used, padded to 4096)
#define WS_QSQ    (WS_NSUM + 4096)          // 528384
#define WS_QNORM  (WS_QSQ + K_ * 4)         // 532480
#define WS_WT     (WS_QNORM + K_ * 4)       // 536576 (NIN_*D_*4 = 131072)
#define WS_END    (WS_WT + NIN_ * D_ * 4)   // 667648 bytes total

// Transpose W (D x C) -> Wt (C x D) so phase-A weight reads are contiguous
// per c (wave-uniform -> s_load), and precompute q_sq / q_norm per code.
__global__ __launch_bounds__(256) void prep_kernel(
    const float* __restrict__ W, const float* __restrict__ emb,
    float* __restrict__ Wt, float* __restrict__ q_sq, float* __restrict__ q_norm)
{
  int t = blockIdx.x * 256 + threadIdx.x;
  if (blockIdx.x < 128) {
    int c = t >> 7, d = t & 127;
    Wt[t] = W[d * NIN_ + c];         // Wt[c*128 + d], coalesced write
  } else {
    int k = t - 128 * 256;           // 0..1023 exactly for blocks 128..131
    if (k < K_) {
      const float* e = emb + (size_t)k * D_;
      float s = 0.f;
      #pragma unroll 8
      for (int d = 0; d < D_; ++d) s = fmaf(e[d], e[d], s);
      q_sq[k] = s;
      q_norm[k] = sqrtf(s);
    }
  }
}

// Fused: ze = W@z, scaled-L2 distance + argmin over K, zq straight-through
// write, EMA scatter-add. Block = 256 threads (4 waves) owns 64 positions.
// Wave w computes d-chunk [32w,32w+32) of ze, then scans code range
// [256w, 256w+256); argmin merged across waves via LDS (first-min ties).
__global__ __launch_bounds__(256, 2) void fused_kernel(
    const float* __restrict__ z, const float* __restrict__ Wt,
    const float* __restrict__ emb, const float* __restrict__ q_sq,
    const float* __restrict__ q_norm, float* __restrict__ out,
    float* __restrict__ z_sum, float* __restrict__ n_sum)
{
  __shared__ float ze_lds[64][132];   // +4 pad
  __shared__ float wbest_s[4][64];
  __shared__ int   wbest_k[4][64];
  __shared__ int   final_k[64];

  const int tid  = threadIdx.x;
  const int lane = tid & 63;          // position within block
  const int wv   = tid >> 6;          // wave id 0..3
  const int p    = blockIdx.x * 64 + lane;
  const int b    = p >> 12;           // p / N_
  const int n    = p & (N_ - 1);

  // ---- phase A: ze[d] for d in [32wv, 32wv+32) -------------------------
  float acc[32];
  #pragma unroll
  for (int j = 0; j < 32; ++j) acc[j] = 0.f;
  const float* zp  = z + (size_t)b * NIN_ * N_ + n;   // z[b,c,n] at zp[c*N_]
  const float* wtp = Wt + wv * 32;                    // Wt[c*128 + 32wv + j]
  for (int c = 0; c < NIN_; ++c) {
    float zv = zp[(size_t)c * N_];                    // coalesced across lanes
    #pragma unroll
    for (int j = 0; j < 32; ++j)
      acc[j] = fmaf(wtp[c * D_ + j], zv, acc[j]);     // wave-uniform -> s_load
  }
  #pragma unroll
  for (int j = 0; j < 32; ++j) ze_lds[lane][wv * 32 + j] = acc[j];
  __syncthreads();

  // full ze row into registers (constant indices -> stays in VGPRs)
  float ze[D_];
  #pragma unroll
  for (int d = 0; d < D_; ++d) ze[d] = ze_lds[lane][d];

  float ze_sq = 0.f;
  #pragma unroll
  for (int d = 0; d < D_; ++d) ze_sq = fmaf(ze[d], ze[d], ze_sq);
  const float zn = sqrtf(ze_sq);

  // ---- phase C: distances + argmin over this wave's 256 codes ----------
  float bs = 3.4028235e38f;
  int   bk = 0;
  const int kbase = wv * (K_ / 4);
  const float* ebase = emb + (size_t)kbase * D_;
  #pragma unroll 2
  for (int kt = 0; kt < K_ / 4; kt += 4) {
    const float* e0 = ebase + (size_t)(kt + 0) * D_;  // wave-uniform -> s_load
    const float* e1 = ebase + (size_t)(kt + 1) * D_;
    const float* e2 = ebase + (size_t)(kt + 2) * D_;
    const float* e3 = ebase + (size_t)(kt + 3) * D_;
    float dot0 = 0.f, dot1 = 0.f, dot2 = 0.f, dot3 = 0.f;
    #pragma unroll
    for (int d = 0; d < D_; ++d) {
      float zd = ze[d];
      dot0 = fmaf(zd, e0[d], dot0);
      dot1 = fmaf(zd, e1[d], dot1);
      dot2 = fmaf(zd, e2[d], dot2);
      dot3 = fmaf(zd, e3[d], dot3);
    }
    #pragma unroll
    for (int t = 0; t < 4; ++t) {
      float dot = (t == 0) ? dot0 : (t == 1) ? dot1 : (t == 2) ? dot2 : dot3;
      int kg = kbase + kt + t;
      float dsq = fmaxf(ze_sq + q_sq[kg] - 2.0f * dot, 0.f);
      float s = sqrtf(dsq) / (zn + q_norm[kg]);
      if (s < bs) { bs = s; bk = kg; }   // strict < keeps first (lowest k) min
    }
  }
  wbest_s[wv][lane] = bs;
  wbest_k[wv][lane] = bk;
  __syncthreads();
  if (wv == 0) {
    float fb = wbest_s[0][lane]; int fk = wbest_k[0][lane];
    #pragma unroll
    for (int w = 1; w < 4; ++w) {        // ascending k-ranges, strict <
      float s = wbest_s[w][lane];
      if (s < fb) { fb = s; fk = wbest_k[w][lane]; }
    }
    final_k[lane] = fk;
  }
  __syncthreads();
  const int kstar = final_k[lane];

  // ---- phase D: zq write (coalesced over n) + EMA scatter-add ----------
  const float* ek  = emb   + (size_t)kstar * D_ + wv * 32;  // per-lane gather
  float*       zsp = z_sum + (size_t)kstar * D_ + wv * 32;
  float*       op  = out + (size_t)b * D_ * N_ + n;
  const int dbase = wv * 32;
  #pragma unroll
  for (int j = 0; j < 32; ++j) {
    float zev = ze_lds[lane][dbase + j];   // dynamic wv -> read LDS, not regs
    float q   = ek[j];
    op[(size_t)(dbase + j) * N_] = zev + (q - zev);  // == zq fwd value, ref order
    atomicAdd(&zsp[j], zev);
  }
  if (wv == 0) atomicAdd(&n_sum[kstar], 1.0f);
}

__global__ __launch_bounds__(256) void finalize_kernel(
    const float* __restrict__ ema_numer, const float* __restrict__ ema_denom,
    const float* __restrict__ z_sum, const float* __restrict__ n_sum,
    float* __restrict__ out)
{
  // float32(0.99) and float32(1.0-0.99) == 0.01f bit-exact vs numpy
  const float G = 0.99f, OMG = 0.01f;
  int t = blockIdx.x * 256 + threadIdx.x;
  float* out_num = out + (size_t)B_ * D_ * N_;
  float* out_den = out_num + K_ * D_;
  if (t < K_ * D_) {
    out_num[t] = G * ema_numer[t] + OMG * z_sum[t];
  } else {
    int k = t - K_ * D_;
    if (k < K_) out_den[k] = G * ema_denom[k] + OMG * n_sum[k];
  }
}

extern "C" void kernel_launch(void* const* d_in, const int* in_sizes, int n_in,
                              void* d_out, int out_size, void* d_ws, size_t ws_size,
                              hipStream_t stream)
{
  (void)in_sizes; (void)n_in; (void)out_size; (void)ws_size;
  const float* z         = (const float*)d_in[0];
  const float* W         = (const float*)d_in[1];
  const float* emb       = (const float*)d_in[2];
  const float* ema_numer = (const float*)d_in[3];
  const float* ema_denom = (const float*)d_in[4];
  float* out = (float*)d_out;
  char*  ws  = (char*)d_ws;
  float* z_sum  = (float*)(ws + WS_ZSUM);
  float* n_sum  = (float*)(ws + WS_NSUM);
  float* q_sq   = (float*)(ws + WS_QSQ);
  float* q_norm = (float*)(ws + WS_QNORM);
  float* Wt     = (float*)(ws + WS_WT);

  // zero the scatter-add accumulators (ws is re-poisoned before every launch)
  hipMemsetAsync(ws, 0, WS_QSQ, stream);

  prep_kernel<<<132, 256, 0, stream>>>(W, emb, Wt, q_sq, q_norm);
  fused_kernel<<<P_ / 64, 256, 0, stream>>>(z, Wt, emb, q_sq, q_norm,
                                            out, z_sum, n_sum);
  finalize_kernel<<<(K_ * D_ + K_) / 256, 256, 0, stream>>>(
      ema_numer, ema_denom, z_sum, n_sum, out);
}

// Round 2
// 643.495 us; speedup vs baseline: 1.7591x; 1.7591x over previous
//
#include <hip/hip_runtime.h>
#include <cmath>

#define B_    8
#define NIN_  256
#define D_    128
#define K_    1024
#define N_    4096
#define P_    (B_ * N_)          // 32768 positions

// ---- workspace layout (bytes) ----
#define WS_ZSUM   0                            // K_*D_*4 = 524288 (zeroed)
#define WS_NSUM   (WS_ZSUM + K_ * D_ * 4)      // 4096 (zeroed)
#define WS_QSQ    (WS_NSUM + 4096)             // K_*4
#define WS_QNORM  (WS_QSQ + K_ * 4)            // K_*4
#define WS_WT     (WS_QNORM + K_ * 4)          // NIN_*D_*4 = 131072
#define WS_ZDM    (WS_WT + NIN_ * D_ * 4)      // D_*P_*4 = 16777216 (d-major ze)
#define WS_ZESQ   (WS_ZDM + (size_t)D_ * P_ * 4)  // P_*4
#define WS_ZEN    (WS_ZESQ + (size_t)P_ * 4)      // P_*4
#define WS_PVAL   (WS_ZEN + (size_t)P_ * 4)       // 8*P_*4
#define WS_PIDX   (WS_PVAL + (size_t)8 * P_ * 4)  // 8*P_*4
// total ~18.9 MiB

// Wt[c][d] = W[d][c] (so per-c weight rows are contiguous -> s_load),
// plus per-code q_sq / q_norm.
__global__ __launch_bounds__(256) void prep_kernel(
    const float* __restrict__ W, const float* __restrict__ emb,
    float* __restrict__ Wt, float* __restrict__ q_sq, float* __restrict__ q_norm)
{
  int t = blockIdx.x * 256 + threadIdx.x;
  if (blockIdx.x < 128) {
    int c = t >> 7, d = t & 127;
    Wt[t] = W[d * NIN_ + c];
  } else {
    int k = t - 128 * 256;
    if (k < K_) {
      const float* e = emb + (size_t)k * D_;
      float s = 0.f;
      #pragma unroll 8
      for (int d = 0; d < D_; ++d) s = fmaf(e[d], e[d], s);
      q_sq[k] = s;
      q_norm[k] = sqrtf(s);
    }
  }
}

// ---- Kernel A: ze = W @ z, stored d-major ze_dm[d][p]; + ze_sq, ze_norm ----
// Block = 64 positions; wave w computes d in [32w, 32w+32).
// z loads coalesced (lane = n); Wt rows wave-uniform -> scalar loads.
__global__ __launch_bounds__(256) void ze_kernel(
    const float* __restrict__ z, const float* __restrict__ Wt,
    float* __restrict__ ze_dm, float* __restrict__ ze_sq,
    float* __restrict__ ze_norm)
{
  __shared__ float sqpart[4][64];
  const int lane = threadIdx.x & 63;
  const int wv   = __builtin_amdgcn_readfirstlane(threadIdx.x >> 6);
  const int p    = blockIdx.x * 64 + lane;
  const int b    = p >> 12;
  const int n    = p & (N_ - 1);

  float acc[32];
  #pragma unroll
  for (int j = 0; j < 32; ++j) acc[j] = 0.f;

  const float* zp = z + (size_t)b * NIN_ * N_ + n;
  const float* wp = Wt + wv * 32;
  #pragma unroll 4
  for (int c = 0; c < NIN_; ++c) {
    float zv = zp[(size_t)c * N_];                 // coalesced v-load
    #pragma unroll
    for (int j = 0; j < 32; ++j)
      acc[j] = fmaf(wp[c * D_ + j], zv, acc[j]);   // wave-uniform -> s_load
  }

  // d-major store: for fixed d, 64 consecutive p -> coalesced
  #pragma unroll
  for (int j = 0; j < 32; ++j)
    ze_dm[(size_t)(wv * 32 + j) * P_ + p] = acc[j];

  float s = 0.f;
  #pragma unroll
  for (int j = 0; j < 32; ++j) s = fmaf(acc[j], acc[j], s);
  sqpart[wv][lane] = s;
  __syncthreads();
  if (wv == 0) {
    float t = sqpart[0][lane];
    t += sqpart[1][lane];
    t += sqpart[2][lane];
    t += sqpart[3][lane];
    ze_sq[p] = t;
    ze_norm[p] = sqrtf(t);
  }
}

// ---- Kernel B: scaled-L2 argmin partials ----
// Wave-task: 64 positions (lane = position) x 128 codes (kb chunk).
// ze[128] VGPR-resident per lane; emb rows wave-uniform -> s_load stream.
// Codes scanned ascending; strict < keeps first (lowest-k) min like np.argmin.
__global__ __launch_bounds__(256, 3) void argmin_kernel(
    const float* __restrict__ ze_dm, const float* __restrict__ ze_sq,
    const float* __restrict__ ze_norm, const float* __restrict__ emb,
    const float* __restrict__ q_sq, const float* __restrict__ q_norm,
    float* __restrict__ pval, int* __restrict__ pidx)
{
  const int lane = threadIdx.x & 63;
  const int wv   = __builtin_amdgcn_readfirstlane(threadIdx.x >> 6);
  const int task = blockIdx.x * 4 + wv;     // 4096 tasks = 512 pos-tiles x 8
  const int kb   = task & 7;
  const int pt   = task >> 3;
  const int p    = pt * 64 + lane;

  float ze[D_];
  #pragma unroll
  for (int d = 0; d < D_; ++d) ze[d] = ze_dm[(size_t)d * P_ + p];  // coalesced
  const float zsq = ze_sq[p];
  const float zn  = ze_norm[p];

  float bs = 3.4028235e38f;
  int   bk = 0;
  const int k0 = kb * (K_ / 8);
  #pragma unroll 2
  for (int kk = 0; kk < K_ / 8; ++kk) {
    const int k = k0 + kk;
    const float* e = emb + (size_t)k * D_;  // wave-uniform -> s_load_dwordx16
    float a0 = 0.f, a1 = 0.f;               // two chains for FMA-latency ILP
    #pragma unroll
    for (int d = 0; d < D_; d += 2) {
      a0 = fmaf(ze[d],     e[d],     a0);
      a1 = fmaf(ze[d + 1], e[d + 1], a1);
    }
    float dot = a0 + a1;
    float dsq = fmaxf(fmaf(-2.0f, dot, zsq + q_sq[k]), 0.0f);
    float sn  = sqrtf(dsq) / (zn + q_norm[k]);
    if (sn < bs) { bs = sn; bk = k; }
  }
  pval[(size_t)kb * P_ + p] = bs;
  pidx[(size_t)kb * P_ + p] = bk;
}

// ---- Kernel D: combine partials, write zq straight-through, EMA scatter ----
__global__ __launch_bounds__(256) void out_kernel(
    const float* __restrict__ ze_dm, const float* __restrict__ emb,
    const float* __restrict__ pval, const int* __restrict__ pidx,
    float* __restrict__ out, float* __restrict__ z_sum,
    float* __restrict__ n_sum)
{
  __shared__ int ks[64];
  const int lane = threadIdx.x & 63;
  const int wv   = __builtin_amdgcn_readfirstlane(threadIdx.x >> 6);
  const int p    = blockIdx.x * 64 + lane;
  const int b    = p >> 12;
  const int n    = p & (N_ - 1);

  if (wv == 0) {
    float bs = pval[p];
    int   bk = pidx[p];
    #pragma unroll
    for (int kb = 1; kb < 8; ++kb) {        // ascending kb, strict <
      float v = pval[(size_t)kb * P_ + p];
      if (v < bs) { bs = v; bk = pidx[(size_t)kb * P_ + p]; }
    }
    ks[lane] = bk;
    atomicAdd(&n_sum[bk], 1.0f);
  }
  __syncthreads();
  const int kst = ks[lane];
  const float* e   = emb   + (size_t)kst * D_ + wv * 32;
  float*       zs  = z_sum + (size_t)kst * D_ + wv * 32;
  float*       op  = out + (size_t)b * D_ * N_ + n;
  const float* zdm = ze_dm + (size_t)(wv * 32) * P_ + p;
  #pragma unroll
  for (int j = 0; j < 32; ++j) {
    float zev = zdm[(size_t)j * P_];                 // coalesced
    float q   = e[j];
    op[(size_t)(wv * 32 + j) * N_] = zev + (q - zev); // ref rounding order
    atomicAdd(&zs[j], zev);
  }
}

__global__ __launch_bounds__(256) void finalize_kernel(
    const float* __restrict__ ema_numer, const float* __restrict__ ema_denom,
    const float* __restrict__ z_sum, const float* __restrict__ n_sum,
    float* __restrict__ out)
{
  const float G = 0.99f, OMG = 0.01f;
  int t = blockIdx.x * 256 + threadIdx.x;
  float* out_num = out + (size_t)B_ * D_ * N_;
  float* out_den = out_num + K_ * D_;
  if (t < K_ * D_) {
    out_num[t] = G * ema_numer[t] + OMG * z_sum[t];
  } else {
    int k = t - K_ * D_;
    if (k < K_) out_den[k] = G * ema_denom[k] + OMG * n_sum[k];
  }
}

extern "C" void kernel_launch(void* const* d_in, const int* in_sizes, int n_in,
                              void* d_out, int out_size, void* d_ws, size_t ws_size,
                              hipStream_t stream)
{
  (void)in_sizes; (void)n_in; (void)out_size; (void)ws_size;
  const float* z         = (const float*)d_in[0];
  const float* W         = (const float*)d_in[1];
  const float* emb       = (const float*)d_in[2];
  const float* ema_numer = (const float*)d_in[3];
  const float* ema_denom = (const float*)d_in[4];
  float* out = (float*)d_out;
  char*  ws  = (char*)d_ws;
  float* z_sum   = (float*)(ws + WS_ZSUM);
  float* n_sum   = (float*)(ws + WS_NSUM);
  float* q_sq    = (float*)(ws + WS_QSQ);
  float* q_norm  = (float*)(ws + WS_QNORM);
  float* Wt      = (float*)(ws + WS_WT);
  float* ze_dm   = (float*)(ws + WS_ZDM);
  float* ze_sq   = (float*)(ws + WS_ZESQ);
  float* ze_norm = (float*)(ws + WS_ZEN);
  float* pval    = (float*)(ws + WS_PVAL);
  int*   pidx    = (int*)(ws + WS_PIDX);

  hipMemsetAsync(ws, 0, WS_QSQ, stream);   // zero z_sum + n_sum

  prep_kernel<<<132, 256, 0, stream>>>(W, emb, Wt, q_sq, q_norm);
  ze_kernel<<<P_ / 64, 256, 0, stream>>>(z, Wt, ze_dm, ze_sq, ze_norm);
  argmin_kernel<<<4096 / 4, 256, 0, stream>>>(ze_dm, ze_sq, ze_norm, emb,
                                              q_sq, q_norm, pval, pidx);
  out_kernel<<<P_ / 64, 256, 0, stream>>>(ze_dm, emb, pval, pidx,
                                          out, z_sum, n_sum);
  finalize_kernel<<<(K_ * D_ + K_) / 256, 256, 0, stream>>>(
      ema_numer, ema_denom, z_sum, n_sum, out);
}

// Round 3
// 369.471 us; speedup vs baseline: 3.0638x; 1.7417x over previous
//
#include <hip/hip_runtime.h>
#include <cmath>

#define B_    8
#define NIN_  256
#define D_    128
#define K_    1024
#define N_    4096
#define P_    (B_ * N_)          // 32768 positions

// ---- workspace layout (bytes) ----
#define WS_ZSUM   0                              // K_*D_*4 = 524288  (zeroed)
#define WS_CNT    (WS_ZSUM + K_ * D_ * 4)        // 4096              (zeroed)
#define WS_OFF    (WS_CNT + 4096)                // 4096
#define WS_QSQ    (WS_OFF + 4096)                // 4096
#define WS_QNORM  (WS_QSQ + 4096)                // 4096
#define WS_KSTAR  (WS_QNORM + 4096)              // P_*4 = 131072
#define WS_RANK   (WS_KSTAR + P_ * 4)            // 131072
#define WS_PLIST  (WS_RANK + P_ * 4)             // 131072
#define WS_WT     (WS_PLIST + P_ * 4)            // NIN_*D_*4 = 131072
#define WS_ZDM    (WS_WT + NIN_ * D_ * 4)        // d-major ze: 16 MiB
#define WS_ZPM    (WS_ZDM + (size_t)D_ * P_ * 4) // p-major ze: 16 MiB
#define WS_ZESQ   (WS_ZPM + (size_t)D_ * P_ * 4) // P_*4
#define WS_ZEN    (WS_ZESQ + (size_t)P_ * 4)     // P_*4
#define WS_PVAL   (WS_ZEN + (size_t)P_ * 4)      // 8*P_*4 = 1 MiB
#define WS_PIDX   (WS_PVAL + (size_t)8 * P_ * 4) // 1 MiB
// total ~37 MiB

__global__ __launch_bounds__(256) void prep_kernel(
    const float* __restrict__ W, const float* __restrict__ emb,
    float* __restrict__ Wt, float* __restrict__ q_sq, float* __restrict__ q_norm)
{
  int t = blockIdx.x * 256 + threadIdx.x;
  if (blockIdx.x < 128) {
    int c = t >> 7, d = t & 127;
    Wt[t] = W[d * NIN_ + c];
  } else {
    int k = t - 128 * 256;
    if (k < K_) {
      const float* e = emb + (size_t)k * D_;
      float s = 0.f;
      #pragma unroll 8
      for (int d = 0; d < D_; ++d) s = fmaf(e[d], e[d], s);
      q_sq[k] = s;
      q_norm[k] = sqrtf(s);
    }
  }
}

// ---- ze = W @ z: stores d-major (for argmin/zq) AND p-major (for gsum) ----
__global__ __launch_bounds__(256) void ze_kernel(
    const float* __restrict__ z, const float* __restrict__ Wt,
    float* __restrict__ ze_dm, float* __restrict__ ze_pm,
    float* __restrict__ ze_sq, float* __restrict__ ze_norm)
{
  __shared__ float tile[64][132];     // +4 pad
  __shared__ float sqpart[4][64];
  const int lane = threadIdx.x & 63;
  const int wv   = __builtin_amdgcn_readfirstlane(threadIdx.x >> 6);
  const int p    = blockIdx.x * 64 + lane;
  const int b    = p >> 12;
  const int n    = p & (N_ - 1);

  float acc[32];
  #pragma unroll
  for (int j = 0; j < 32; ++j) acc[j] = 0.f;

  const float* zp = z + (size_t)b * NIN_ * N_ + n;
  const float* wp = Wt + wv * 32;
  #pragma unroll 4
  for (int c = 0; c < NIN_; ++c) {
    float zv = zp[(size_t)c * N_];                 // coalesced v-load
    #pragma unroll
    for (int j = 0; j < 32; ++j)
      acc[j] = fmaf(wp[c * D_ + j], zv, acc[j]);   // wave-uniform -> s_load
  }

  #pragma unroll
  for (int j = 0; j < 32; ++j) {
    ze_dm[(size_t)(wv * 32 + j) * P_ + p] = acc[j]; // d-major, coalesced
    tile[lane][wv * 32 + j] = acc[j];
  }
  float s = 0.f;
  #pragma unroll
  for (int j = 0; j < 32; ++j) s = fmaf(acc[j], acc[j], s);
  sqpart[wv][lane] = s;
  __syncthreads();

  if (wv == 0) {
    float t = sqpart[0][lane];
    t += sqpart[1][lane];
    t += sqpart[2][lane];
    t += sqpart[3][lane];
    ze_sq[p] = t;
    ze_norm[p] = sqrtf(t);
  }
  // p-major store via LDS transpose: 8 rounds x (8 rows x 128 cols) float4
  const int row = threadIdx.x >> 5;          // 0..7
  const int c4  = (threadIdx.x & 31) * 4;    // 0..124
  #pragma unroll
  for (int r = 0; r < 8; ++r) {
    int pr = r * 8 + row;
    float4 v = *(const float4*)&tile[pr][c4];
    *(float4*)&ze_pm[(size_t)(blockIdx.x * 64 + pr) * D_ + c4] = v;
  }
}

// ---- argmin partials: wave-task = 64 positions x 128 codes ----
__global__ __launch_bounds__(256, 3) void argmin_kernel(
    const float* __restrict__ ze_dm, const float* __restrict__ ze_sq,
    const float* __restrict__ ze_norm, const float* __restrict__ emb,
    const float* __restrict__ q_sq, const float* __restrict__ q_norm,
    float* __restrict__ pval, int* __restrict__ pidx)
{
  const int lane = threadIdx.x & 63;
  const int wv   = __builtin_amdgcn_readfirstlane(threadIdx.x >> 6);
  const int task = blockIdx.x * 4 + wv;     // 4096 tasks
  const int kb   = task & 7;
  const int pt   = task >> 3;
  const int p    = pt * 64 + lane;

  float ze[D_];
  #pragma unroll
  for (int d = 0; d < D_; ++d) ze[d] = ze_dm[(size_t)d * P_ + p];
  const float zsq = ze_sq[p];
  const float zn  = ze_norm[p];

  float bs = 3.4028235e38f;
  int   bk = 0;
  const int k0 = kb * (K_ / 8);
  #pragma unroll 2
  for (int kk = 0; kk < K_ / 8; kk += 2) {   // 2 codes per iter for ILP
    const int ka = k0 + kk, kc = ka + 1;
    const float* ea = emb + (size_t)ka * D_; // wave-uniform -> s_load stream
    const float* ec = ea + D_;
    float a0 = 0.f, a1 = 0.f, c0 = 0.f, c1 = 0.f;
    #pragma unroll
    for (int d = 0; d < D_; d += 2) {
      a0 = fmaf(ze[d],     ea[d],     a0);
      a1 = fmaf(ze[d + 1], ea[d + 1], a1);
      c0 = fmaf(ze[d],     ec[d],     c0);
      c1 = fmaf(ze[d + 1], ec[d + 1], c1);
    }
    float dota = a0 + a1, dotc = c0 + c1;
    float dsqa = fmaxf(fmaf(-2.0f, dota, zsq + q_sq[ka]), 0.0f);
    float sa   = sqrtf(dsqa) / (zn + q_norm[ka]);
    if (sa < bs) { bs = sa; bk = ka; }       // strict < == np first-min
    float dsqc = fmaxf(fmaf(-2.0f, dotc, zsq + q_sq[kc]), 0.0f);
    float sc   = sqrtf(dsqc) / (zn + q_norm[kc]);
    if (sc < bs) { bs = sc; bk = kc; }
  }
  pval[(size_t)kb * P_ + p] = bs;
  pidx[(size_t)kb * P_ + p] = bk;
}

// ---- combine partials -> kstar, rank (int atomics only) ----
__global__ __launch_bounds__(256) void combine_kernel(
    const float* __restrict__ pval, const int* __restrict__ pidx,
    int* __restrict__ kstar, int* __restrict__ rank, int* __restrict__ counts)
{
  const int p = blockIdx.x * 256 + threadIdx.x;
  float bs = pval[p];
  int   bk = pidx[p];
  #pragma unroll
  for (int kb = 1; kb < 8; ++kb) {           // ascending kb, strict <
    float v = pval[(size_t)kb * P_ + p];
    if (v < bs) { bs = v; bk = pidx[(size_t)kb * P_ + p]; }
  }
  kstar[p] = bk;
  rank[p] = atomicAdd(&counts[bk], 1);
}

// ---- exclusive prefix over counts; fold ema_denom output ----
__global__ __launch_bounds__(1024) void prefix_kernel(
    const int* __restrict__ counts, const float* __restrict__ ema_denom,
    int* __restrict__ offsets, float* __restrict__ out_den)
{
  __shared__ int s[1024];
  const int t = threadIdx.x;
  const int c = counts[t];
  s[t] = c;
  __syncthreads();
  for (int off = 1; off < 1024; off <<= 1) {
    int v = (t >= off) ? s[t - off] : 0;
    __syncthreads();
    s[t] += v;
    __syncthreads();
  }
  offsets[t] = s[t] - c;                      // exclusive
  out_den[t] = 0.99f * ema_denom[t] + 0.01f * (float)c;
}

__global__ __launch_bounds__(256) void scatter_kernel(
    const int* __restrict__ kstar, const int* __restrict__ rank,
    const int* __restrict__ offsets, int* __restrict__ pos_list)
{
  const int p = blockIdx.x * 256 + threadIdx.x;
  pos_list[offsets[kstar[p]] + rank[p]] = p;
}

// ---- zq straight-through write (no atomics) ----
__global__ __launch_bounds__(256) void zq_kernel(
    const float* __restrict__ ze_dm, const float* __restrict__ emb,
    const int* __restrict__ kstar, float* __restrict__ out)
{
  const int lane = threadIdx.x & 63;
  const int wv   = __builtin_amdgcn_readfirstlane(threadIdx.x >> 6);
  const int p    = blockIdx.x * 64 + lane;
  const int b    = p >> 12;
  const int n    = p & (N_ - 1);
  const int kst  = kstar[p];
  const float* e   = emb + (size_t)kst * D_ + wv * 32;   // per-lane gather (L2)
  float*       op  = out + (size_t)b * D_ * N_ + n;
  const float* zdm = ze_dm + (size_t)(wv * 32) * P_ + p;
  #pragma unroll
  for (int j = 0; j < 32; ++j) {
    float zev = zdm[(size_t)j * P_];            // coalesced
    float q   = e[j];
    op[(size_t)(wv * 32 + j) * N_] = zev + (q - zev);  // ref rounding order
  }
}

// ---- segment-sum over sorted positions; flush on code boundary ----
__global__ __launch_bounds__(128) void gsum_kernel(
    const float* __restrict__ ze_pm, const int* __restrict__ pos_list,
    const int* __restrict__ kstar, float* __restrict__ z_sum)
{
  const int d  = threadIdx.x;                 // 0..127
  const int i0 = blockIdx.x * 32;             // 1024 blocks x 32 positions
  int   kprev = -1;
  float acc = 0.f;
  #pragma unroll 4
  for (int ii = 0; ii < 32; ++ii) {
    int p = pos_list[i0 + ii];                // uniform -> s_load
    int k = kstar[p];
    if (k != kprev) {                         // block-uniform branch
      if (kprev >= 0) atomicAdd(&z_sum[(size_t)kprev * D_ + d], acc);
      acc = 0.f;
      kprev = k;
    }
    acc += ze_pm[(size_t)p * D_ + d];         // coalesced 512B
  }
  if (kprev >= 0) atomicAdd(&z_sum[(size_t)kprev * D_ + d], acc);
}

__global__ __launch_bounds__(256) void finalize_num_kernel(
    const float* __restrict__ ema_numer, const float* __restrict__ z_sum,
    float* __restrict__ out)
{
  const int t = blockIdx.x * 256 + threadIdx.x;   // K_*D_ threads
  float* out_num = out + (size_t)B_ * D_ * N_;
  out_num[t] = 0.99f * ema_numer[t] + 0.01f * z_sum[t];
}

extern "C" void kernel_launch(void* const* d_in, const int* in_sizes, int n_in,
                              void* d_out, int out_size, void* d_ws, size_t ws_size,
                              hipStream_t stream)
{
  (void)in_sizes; (void)n_in; (void)out_size; (void)ws_size;
  const float* z         = (const float*)d_in[0];
  const float* W         = (const float*)d_in[1];
  const float* emb       = (const float*)d_in[2];
  const float* ema_numer = (const float*)d_in[3];
  const float* ema_denom = (const float*)d_in[4];
  float* out = (float*)d_out;
  char*  ws  = (char*)d_ws;
  float* z_sum   = (float*)(ws + WS_ZSUM);
  int*   counts  = (int*)(ws + WS_CNT);
  int*   offsets = (int*)(ws + WS_OFF);
  float* q_sq    = (float*)(ws + WS_QSQ);
  float* q_norm  = (float*)(ws + WS_QNORM);
  int*   kstar   = (int*)(ws + WS_KSTAR);
  int*   rank    = (int*)(ws + WS_RANK);
  int*   plist   = (int*)(ws + WS_PLIST);
  float* Wt      = (float*)(ws + WS_WT);
  float* ze_dm   = (float*)(ws + WS_ZDM);
  float* ze_pm   = (float*)(ws + WS_ZPM);
  float* ze_sq   = (float*)(ws + WS_ZESQ);
  float* ze_norm = (float*)(ws + WS_ZEN);
  float* pval    = (float*)(ws + WS_PVAL);
  int*   pidx    = (int*)(ws + WS_PIDX);
  float* out_den = out + (size_t)B_ * D_ * N_ + K_ * D_;

  hipMemsetAsync(ws, 0, WS_OFF, stream);       // zero z_sum + counts

  prep_kernel<<<132, 256, 0, stream>>>(W, emb, Wt, q_sq, q_norm);
  ze_kernel<<<P_ / 64, 256, 0, stream>>>(z, Wt, ze_dm, ze_pm, ze_sq, ze_norm);
  argmin_kernel<<<4096 / 4, 256, 0, stream>>>(ze_dm, ze_sq, ze_norm, emb,
                                              q_sq, q_norm, pval, pidx);
  combine_kernel<<<P_ / 256, 256, 0, stream>>>(pval, pidx, kstar, rank, counts);
  prefix_kernel<<<1, 1024, 0, stream>>>(counts, ema_denom, offsets, out_den);
  scatter_kernel<<<P_ / 256, 256, 0, stream>>>(kstar, rank, offsets, plist);
  zq_kernel<<<P_ / 64, 256, 0, stream>>>(ze_dm, emb, kstar, out);
  gsum_kernel<<<P_ / 32, 128, 0, stream>>>(ze_pm, plist, kstar, z_sum);
  finalize_num_kernel<<<K_ * D_ / 256, 256, 0, stream>>>(ema_numer, z_sum, out);
}

// Round 4
// 319.687 us; speedup vs baseline: 3.5410x; 1.1557x over previous
//
#include <hip/hip_runtime.h>
#include <cmath>

#define B_    8
#define NIN_  256
#define D_    128
#define K_    1024
#define N_    4096
#define P_    (B_ * N_)          // 32768 positions

// ---- workspace layout (bytes) ----
#define WS_ZSUM   0                              // K_*D_*4 = 524288 (zeroed)
#define WS_CNT    (WS_ZSUM + K_ * D_ * 4)        // 4096             (zeroed)
#define WS_OFF    (WS_CNT + 4096)                // 4096
#define WS_QSQ    (WS_OFF + 4096)                // 4096
#define WS_QNORM  (WS_QSQ + 4096)                // 4096
#define WS_KSTAR  (WS_QNORM + 4096)              // P_*4 = 131072
#define WS_RANK   (WS_KSTAR + P_ * 4)            // 131072
#define WS_PLIST  (WS_RANK + P_ * 4)             // 131072
#define WS_KLIST  (WS_PLIST + P_ * 4)            // 131072
#define WS_WT     (WS_KLIST + P_ * 4)            // NIN_*D_*4 = 131072
#define WS_ZDM    (WS_WT + NIN_ * D_ * 4)        // d-major ze: 16 MiB
#define WS_ZPM    (WS_ZDM + (size_t)D_ * P_ * 4) // p-major ze: 16 MiB
#define WS_ZESQ   (WS_ZPM + (size_t)D_ * P_ * 4) // P_*4
#define WS_ZEN    (WS_ZESQ + (size_t)P_ * 4)     // P_*4
// total ~34 MiB

__global__ __launch_bounds__(256) void prep_kernel(
    const float* __restrict__ W, const float* __restrict__ emb,
    float* __restrict__ Wt, float* __restrict__ q_sq, float* __restrict__ q_norm)
{
  int t = blockIdx.x * 256 + threadIdx.x;
  if (blockIdx.x < 128) {
    int c = t >> 7, d = t & 127;
    Wt[t] = W[d * NIN_ + c];
  } else {
    int k = t - 128 * 256;
    if (k < K_) {
      const float* e = emb + (size_t)k * D_;
      float s = 0.f;
      #pragma unroll 8
      for (int d = 0; d < D_; ++d) s = fmaf(e[d], e[d], s);
      q_sq[k] = s;
      q_norm[k] = sqrtf(s);
    }
  }
}

// ---- ze = W @ z. Block = 512 thr (8 waves) x 64 positions; wave wv does
// d-chunk [16wv,16wv+16). Stores d-major (argmin) + p-major (gsum). ----
__global__ __launch_bounds__(512) void ze_kernel(
    const float* __restrict__ z, const float* __restrict__ Wt,
    float* __restrict__ ze_dm, float* __restrict__ ze_pm,
    float* __restrict__ ze_sq, float* __restrict__ ze_norm)
{
  __shared__ float tile[64][132];     // +4 pad
  __shared__ float sqpart[8][64];
  const int t    = threadIdx.x;
  const int lane = t & 63;
  const int wv   = __builtin_amdgcn_readfirstlane(t >> 6);   // 0..7
  const int p    = blockIdx.x * 64 + lane;
  const int b    = p >> 12;
  const int n    = p & (N_ - 1);

  float acc[16];
  #pragma unroll
  for (int j = 0; j < 16; ++j) acc[j] = 0.f;

  const float* zp = z + (size_t)b * NIN_ * N_ + n;
  const float* wp = Wt + wv * 16;
  #pragma unroll 4
  for (int c = 0; c < NIN_; ++c) {
    float zv = zp[(size_t)c * N_];                 // coalesced v-load
    #pragma unroll
    for (int j = 0; j < 16; ++j)
      acc[j] = fmaf(wp[c * D_ + j], zv, acc[j]);   // wave-uniform -> s_load
  }

  #pragma unroll
  for (int j = 0; j < 16; ++j) {
    ze_dm[(size_t)(wv * 16 + j) * P_ + p] = acc[j];  // coalesced
    tile[lane][wv * 16 + j] = acc[j];
  }
  float s = 0.f;
  #pragma unroll
  for (int j = 0; j < 16; ++j) s = fmaf(acc[j], acc[j], s);
  sqpart[wv][lane] = s;
  __syncthreads();

  if (wv == 0) {
    float tt = sqpart[0][lane];
    #pragma unroll
    for (int w = 1; w < 8; ++w) tt += sqpart[w][lane];
    ze_sq[p] = tt;
    ze_norm[p] = sqrtf(tt);
  }
  // p-major store via LDS transpose
  const int row = t >> 5;              // 0..15
  const int c4  = (t & 31) * 4;        // 0..124
  #pragma unroll
  for (int r = 0; r < 4; ++r) {
    int pr = r * 16 + row;
    float4 v = *(const float4*)&tile[pr][c4];
    *(float4*)&ze_pm[(size_t)(blockIdx.x * 64 + pr) * D_ + c4] = v;
  }
}

// ---- fused argmin + zq + rank. Block = 512 thr (8 waves) x 64 positions.
// ze tile lives in LDS d-major: 1 conflict-free ds_read_b32 per d, reused
// across an 8-code tile (128 ds vs 1024 FMA). Wave wv scans codes
// [128wv, 128wv+128); cross-wave combine keeps np.argmin first-min ties. ----
__global__ __launch_bounds__(512) void argmin_zq_kernel(
    const float* __restrict__ ze_dm, const float* __restrict__ ze_sq,
    const float* __restrict__ ze_norm, const float* __restrict__ emb,
    const float* __restrict__ q_sq, const float* __restrict__ q_norm,
    int* __restrict__ kstar, int* __restrict__ rank, int* __restrict__ counts,
    float* __restrict__ out)
{
  __shared__ float lds_ze[128 * 64];   // 32 KiB, d-major
  __shared__ float wbest_s[8][64];
  __shared__ int   wbest_k[8][64];
  __shared__ int   ks[64];
  const int t    = threadIdx.x;
  const int lane = t & 63;
  const int wv   = __builtin_amdgcn_readfirstlane(t >> 6);   // 0..7
  const int p    = blockIdx.x * 64 + lane;

  // stage ze tile: wave wv loads d = 8r+wv rows, coalesced over p
  #pragma unroll
  for (int r = 0; r < 16; ++r) {
    int d = r * 8 + wv;
    lds_ze[d * 64 + lane] = ze_dm[(size_t)d * P_ + p];
  }
  const float zsq = ze_sq[p];
  const float zn  = ze_norm[p];
  __syncthreads();

  float bs = 3.4028235e38f;
  int   bk = 0;
  const int k0 = wv * 128;
  for (int kt = 0; kt < 16; ++kt) {
    const int kb = k0 + kt * 8;
    const float* e = emb + (size_t)kb * D_;      // wave-uniform -> s_load
    float acc[8];
    #pragma unroll
    for (int j = 0; j < 8; ++j) acc[j] = 0.f;
    #pragma unroll 8
    for (int d = 0; d < D_; ++d) {
      float zed = lds_ze[d * 64 + lane];         // 1 ds_read, 8 uses
      #pragma unroll
      for (int j = 0; j < 8; ++j)
        acc[j] = fmaf(zed, e[j * D_ + d], acc[j]);
    }
    #pragma unroll
    for (int j = 0; j < 8; ++j) {                // ascending k, strict <
      const int k = kb + j;
      float dsq = fmaxf(fmaf(-2.0f, acc[j], zsq + q_sq[k]), 0.0f);
      float sn  = sqrtf(dsq) / (zn + q_norm[k]);
      if (sn < bs) { bs = sn; bk = k; }
    }
  }
  wbest_s[wv][lane] = bs;
  wbest_k[wv][lane] = bk;
  __syncthreads();
  if (wv == 0) {
    float fb = wbest_s[0][lane];
    int   fk = wbest_k[0][lane];
    #pragma unroll
    for (int w = 1; w < 8; ++w) {                // ascending k-ranges
      float v = wbest_s[w][lane];
      if (v < fb) { fb = v; fk = wbest_k[w][lane]; }
    }
    ks[lane]  = fk;
    kstar[p]  = fk;
    rank[p]   = atomicAdd(&counts[fk], 1);
  }
  __syncthreads();

  // zq straight-through write: wave wv writes d-chunk [16wv,16wv+16)
  const int kst = ks[lane];
  const int b   = p >> 12;
  const int n   = p & (N_ - 1);
  float*       op = out + (size_t)b * D_ * N_ + n;
  const float* ek = emb + (size_t)kst * D_ + wv * 16;  // per-lane gather (L2)
  #pragma unroll
  for (int j = 0; j < 16; ++j) {
    float zev = lds_ze[(wv * 16 + j) * 64 + lane];
    float q   = ek[j];
    op[(size_t)(wv * 16 + j) * N_] = zev + (q - zev);  // ref rounding order
  }
}

// ---- exclusive prefix over counts; fold ema_denom output ----
__global__ __launch_bounds__(1024) void prefix_kernel(
    const int* __restrict__ counts, const float* __restrict__ ema_denom,
    int* __restrict__ offsets, float* __restrict__ out_den)
{
  __shared__ int s[1024];
  const int t = threadIdx.x;
  const int c = counts[t];
  s[t] = c;
  __syncthreads();
  for (int off = 1; off < 1024; off <<= 1) {
    int v = (t >= off) ? s[t - off] : 0;
    __syncthreads();
    s[t] += v;
    __syncthreads();
  }
  offsets[t] = s[t] - c;                      // exclusive
  out_den[t] = 0.99f * ema_denom[t] + 0.01f * (float)c;
}

__global__ __launch_bounds__(256) void scatter_kernel(
    const int* __restrict__ kstar, const int* __restrict__ rank,
    const int* __restrict__ offsets, int* __restrict__ pos_list,
    int* __restrict__ k_list)
{
  const int p = blockIdx.x * 256 + threadIdx.x;
  const int k = kstar[p];
  const int slot = offsets[k] + rank[p];
  pos_list[slot] = p;
  k_list[slot] = k;        // sorted codes: gsum reads linearly (no dep chain)
}

// ---- segment-sum over sorted positions; flush on code boundary ----
__global__ __launch_bounds__(128) void gsum_kernel(
    const float* __restrict__ ze_pm, const int* __restrict__ pos_list,
    const int* __restrict__ k_list, float* __restrict__ z_sum)
{
  const int d  = threadIdx.x;                 // 0..127
  const int i0 = blockIdx.x * 32;             // 1024 blocks x 32 slots
  int   kprev = -1;
  float acc = 0.f;
  #pragma unroll
  for (int ii = 0; ii < 32; ++ii) {
    int p = pos_list[i0 + ii];                // uniform, linear -> s_load batch
    int k = k_list[i0 + ii];                  // uniform, linear
    if (k != kprev) {                         // block-uniform branch
      if (kprev >= 0) atomicAdd(&z_sum[(size_t)kprev * D_ + d], acc);
      acc = 0.f;
      kprev = k;
    }
    acc += ze_pm[(size_t)p * D_ + d];         // coalesced 512B row
  }
  if (kprev >= 0) atomicAdd(&z_sum[(size_t)kprev * D_ + d], acc);
}

__global__ __launch_bounds__(256) void finalize_num_kernel(
    const float* __restrict__ ema_numer, const float* __restrict__ z_sum,
    float* __restrict__ out)
{
  const int t = blockIdx.x * 256 + threadIdx.x;   // K_*D_ threads
  float* out_num = out + (size_t)B_ * D_ * N_;
  out_num[t] = 0.99f * ema_numer[t] + 0.01f * z_sum[t];
}

extern "C" void kernel_launch(void* const* d_in, const int* in_sizes, int n_in,
                              void* d_out, int out_size, void* d_ws, size_t ws_size,
                              hipStream_t stream)
{
  (void)in_sizes; (void)n_in; (void)out_size; (void)ws_size;
  const float* z         = (const float*)d_in[0];
  const float* W         = (const float*)d_in[1];
  const float* emb       = (const float*)d_in[2];
  const float* ema_numer = (const float*)d_in[3];
  const float* ema_denom = (const float*)d_in[4];
  float* out = (float*)d_out;
  char*  ws  = (char*)d_ws;
  float* z_sum   = (float*)(ws + WS_ZSUM);
  int*   counts  = (int*)(ws + WS_CNT);
  int*   offsets = (int*)(ws + WS_OFF);
  float* q_sq    = (float*)(ws + WS_QSQ);
  float* q_norm  = (float*)(ws + WS_QNORM);
  int*   kstar   = (int*)(ws + WS_KSTAR);
  int*   rank    = (int*)(ws + WS_RANK);
  int*   plist   = (int*)(ws + WS_PLIST);
  int*   klist   = (int*)(ws + WS_KLIST);
  float* Wt      = (float*)(ws + WS_WT);
  float* ze_dm   = (float*)(ws + WS_ZDM);
  float* ze_pm   = (float*)(ws + WS_ZPM);
  float* ze_sq   = (float*)(ws + WS_ZESQ);
  float* ze_norm = (float*)(ws + WS_ZEN);
  float* out_den = out + (size_t)B_ * D_ * N_ + K_ * D_;

  hipMemsetAsync(ws, 0, WS_OFF, stream);       // zero z_sum + counts

  prep_kernel<<<132, 256, 0, stream>>>(W, emb, Wt, q_sq, q_norm);
  ze_kernel<<<P_ / 64, 512, 0, stream>>>(z, Wt, ze_dm, ze_pm, ze_sq, ze_norm);
  argmin_zq_kernel<<<P_ / 64, 512, 0, stream>>>(ze_dm, ze_sq, ze_norm, emb,
                                                q_sq, q_norm, kstar, rank,
                                                counts, out);
  prefix_kernel<<<1, 1024, 0, stream>>>(counts, ema_denom, offsets, out_den);
  scatter_kernel<<<P_ / 256, 256, 0, stream>>>(kstar, rank, offsets, plist, klist);
  gsum_kernel<<<P_ / 32, 128, 0, stream>>>(ze_pm, plist, klist, z_sum);
  finalize_num_kernel<<<K_ * D_ / 256, 256, 0, stream>>>(ema_numer, z_sum, out);
}